// Round 5
// baseline (88.562 us; speedup 1.0000x reference)
//
#include <hip/hip_runtime.h>
#include <hip/hip_bf16.h>
#include <math.h>

#define D     128
#define NT    256            // B*T
#define HD    32
#define LD    32
#define NCH   4              // n's per (i,j)-tile block
#define NC    (NT/NCH)       // 64 chunks
#define NROWS (NT*D)         // 32768
#define NBLK  256            // == CU count; 1 block/CU, co-resident

static __device__ inline unsigned short f2bf(float f) {
    __hip_bfloat16 b = __float2bfloat16(f);
    return *reinterpret_cast<unsigned short*>(&b);
}

struct P1 { float W1a[HD][33]; float W1b[HD][33]; };
struct P2 { float spa[NCH][64][36]; float spb[NCH][64][32]; float sS[64][65]; };
union Smem { P1 p1; P2 p2; };

// device-scope grid barrier: monotonic counter (memset to 0 each call),
// agent-scope acq/rel -> buffer_wbl2 / buffer_inv on gfx950 (XCD coherence)
static __device__ inline void grid_barrier(unsigned* cnt) {
    __syncthreads();
    if (threadIdx.x == 0) {
        __threadfence();  // agent acq_rel fence: flush L2 writebacks
        __hip_atomic_fetch_add(cnt, 1u, __ATOMIC_ACQ_REL, __HIP_MEMORY_SCOPE_AGENT);
        while (__hip_atomic_load(cnt, __ATOMIC_ACQUIRE, __HIP_MEMORY_SCOPE_AGENT)
               < (unsigned)NBLK)
            __builtin_amdgcn_s_sleep(2);
        __threadfence();
    }
    __syncthreads();
}

__global__ __launch_bounds__(512) void fused_all(
    const float* __restrict__ z, const float* __restrict__ Wmag,
    const float* __restrict__ W1, const float* __restrict__ b1,
    const float* __restrict__ W2,
    float* __restrict__ pa, float* __restrict__ pb,
    float* __restrict__ ca2, float* __restrict__ cb2,
    __hip_bfloat16* __restrict__ Spart, __hip_bfloat16* __restrict__ SpartT,
    unsigned* __restrict__ cnt, float* __restrict__ out)
{
    __shared__ Smem sm;
    const int t   = threadIdx.x;
    const int bid = blockIdx.x;

    // ================= phase 1: pa/pb/ca2/cb2 (block bid == token n) ======
    {
        for (int f = t; f < HD * 2 * LD; f += 512) {
            int hh = f >> 6, c = f & 63;
            float v = W1[f];
            if (c < LD) sm.p1.W1a[hh][c] = v; else sm.p1.W1b[hh][c - LD] = v;
        }
        __syncthreads();

        const int h    = t & 31;
        const int slot = t >> 5;              // 0..15
        float wa[LD], wb[LD];
        #pragma unroll
        for (int k = 0; k < 8; ++k) {
            *(float4*)&wa[k * 4] = *(const float4*)&sm.p1.W1a[h][k * 4];
            *(float4*)&wb[k * 4] = *(const float4*)&sm.p1.W1b[h][k * 4];
        }
        const float bias = b1[h];
        const float w2h  = 0.5f * W2[h];

        #pragma unroll 2
        for (int q = 0; q < 8; ++q) {
            const int r   = slot + 16 * q;    // 0..127 (= output index i)
            const int row = bid * D + r;      // n = bid
            const float* zr = z + (size_t)row * LD;
            float aA = bias, aB = 0.f;
            #pragma unroll
            for (int k = 0; k < 8; ++k) {
                float4 v = *(const float4*)&zr[k * 4];
                aA = fmaf(v.x, wa[k*4+0], aA); aA = fmaf(v.y, wa[k*4+1], aA);
                aA = fmaf(v.z, wa[k*4+2], aA); aA = fmaf(v.w, wa[k*4+3], aA);
                aB = fmaf(v.x, wb[k*4+0], aB); aB = fmaf(v.y, wb[k*4+1], aB);
                aB = fmaf(v.z, wb[k*4+2], aB); aB = fmaf(v.w, wb[k*4+3], aB);
            }
            pa[row * HD + h] = aA;
            pb[row * HD + h] = aB;
            float vA = w2h * aA, vB = w2h * aB;
            #pragma unroll
            for (int m = 16; m >= 1; m >>= 1) {
                vA += __shfl_xor(vA, m, 32);
                vB += __shfl_xor(vB, m, 32);
            }
            if (h == 0) { ca2[row] = vA; cb2[row] = vB; }
        }
    }

    grid_barrier(&cnt[0]);

    // ================= phase 2: scores tile =============================
    // bid -> nc = bid>>2, ij = bid&3
    {
        const int nc = bid >> 2;
        const int i0 = (bid & 1) * 64;
        const int j0 = ((bid >> 1) & 1) * 64;

        for (int f = t; f < NCH * 64 * 8; f += 512) {
            int h4 = f & 7, row = (f >> 3) & 63, nn = f >> 9;
            int n = nc * NCH + nn;
            *(float4*)&sm.p2.spa[nn][row][h4 * 4] =
                *(const float4*)&pa[((n * D) + i0 + row) * HD + h4 * 4];
            *(float4*)&sm.p2.spb[nn][row][h4 * 4] =
                *(const float4*)&pb[((n * D) + j0 + row) * HD + h4 * 4];
        }

        float w2r[HD];
        #pragma unroll
        for (int hh = 0; hh < HD; ++hh) w2r[hh] = 0.5f * W2[hh];

        __syncthreads();

        const int lane = t & 63;
        const int jb   = __builtin_amdgcn_readfirstlane((t >> 6) * 8);

        float accA[8], accB[8];
        #pragma unroll
        for (int jj = 0; jj < 8; ++jj) { accA[jj] = 0.f; accB[jj] = 0.f; }

        for (int nn = 0; nn < NCH; ++nn) {
            float par[HD];
            #pragma unroll
            for (int k = 0; k < 8; ++k)
                *(float4*)&par[k * 4] = *(const float4*)&sm.p2.spa[nn][lane][k * 4];
            const int n = nc * NCH + nn;
            const float cai = ca2[n * D + i0 + lane];
            #pragma unroll
            for (int jj = 0; jj < 8; ++jj) {
                const int j = jb + jj;
                float a = accA[jj] + (cai + cb2[n * D + j0 + j]);
                float b = accB[jj];
                #pragma unroll
                for (int k = 0; k < 4; ++k) {
                    float4 v = *(const float4*)&sm.p2.spb[nn][j][k * 4];
                    a = fmaf(w2r[k*4+0], fabsf(par[k*4+0] + v.x), a);
                    a = fmaf(w2r[k*4+1], fabsf(par[k*4+1] + v.y), a);
                    a = fmaf(w2r[k*4+2], fabsf(par[k*4+2] + v.z), a);
                    a = fmaf(w2r[k*4+3], fabsf(par[k*4+3] + v.w), a);
                }
                #pragma unroll
                for (int k = 4; k < 8; ++k) {
                    float4 v = *(const float4*)&sm.p2.spb[nn][j][k * 4];
                    b = fmaf(w2r[k*4+0], fabsf(par[k*4+0] + v.x), b);
                    b = fmaf(w2r[k*4+1], fabsf(par[k*4+1] + v.y), b);
                    b = fmaf(w2r[k*4+2], fabsf(par[k*4+2] + v.z), b);
                    b = fmaf(w2r[k*4+3], fabsf(par[k*4+3] + v.w), b);
                }
                accA[jj] = a; accB[jj] = b;
            }
        }

        // bf16 partials, both orientations, coalesced
        {
            __hip_bfloat16* SpT = SpartT + ((size_t)nc * D + j0 + jb) * D + i0;
            #pragma unroll
            for (int jj = 0; jj < 8; ++jj)
                SpT[jj * D + lane] = __float2bfloat16(accA[jj] + accB[jj]);
        }
        #pragma unroll
        for (int jj = 0; jj < 8; ++jj)
            sm.p2.sS[lane][jb + jj] = accA[jj] + accB[jj];
        __syncthreads();
        {
            int ir = t >> 3;
            int jc = (t & 7) * 8;
            unsigned int pk[4];
            #pragma unroll
            for (int k = 0; k < 4; ++k) {
                unsigned int lo = f2bf(sm.p2.sS[ir][jc + 2 * k]);
                unsigned int hi = f2bf(sm.p2.sS[ir][jc + 2 * k + 1]);
                pk[k] = (hi << 16) | lo;
            }
            __hip_bfloat16* Sp = Spart + ((size_t)nc * D + i0 + ir) * D + j0 + jc;
            *(uint4*)Sp = *(uint4*)pk;
        }
    }

    grid_barrier(&cnt[1]);

    // ================= phase 3: finalize ================================
    {
        const int idx = bid * 64 + (t >> 3);      // 0..16383
        const int i = idx >> 7, j = idx & 127;
        const int ncg = t & 7;

        float s = 0.f;
        #pragma unroll
        for (int q = 0; q < 8; ++q) {
            int c = ncg * 8 + q;
            s += __bfloat162float(Spart [(size_t)c * D * D + idx])
               - __bfloat162float(SpartT[(size_t)c * D * D + idx]);
        }
        s += __shfl_xor(s, 1);
        s += __shfl_xor(s, 2);
        s += __shfl_xor(s, 4);

        if (ncg == 0) {
            float av  = s * (1.0f / 256.0f);      // mean over n; TAU=1, b2 cancels
            float dir = 1.0f / (1.0f + __expf(-av));
            float wm  = 0.5f * (Wmag[i * D + j] + Wmag[j * D + i]);
            float A;
            if (i == j) { wm = 0.f; A = 0.f; }
            else        { A = dir / (1.0f + __expf(-wm)); }
            out[idx]         = A;
            out[D * D + idx] = wm;
        }
    }
}

extern "C" void kernel_launch(void* const* d_in, const int* in_sizes, int n_in,
                              void* d_out, int out_size, void* d_ws, size_t ws_size,
                              hipStream_t stream)
{
    const float* z    = (const float*)d_in[0];   // (4,64,128,32)
    const float* Wmag = (const float*)d_in[1];   // (128,128)
    const float* W1   = (const float*)d_in[2];   // (32,64)
    const float* b1   = (const float*)d_in[3];   // (32,)
    const float* W2   = (const float*)d_in[4];   // (1,32)
    // d_in[5] = b2: cancels in scores - scores^T.

    float* pa   = (float*)d_ws;                          // 4 MB
    float* pb   = pa + (size_t)NROWS * HD;               // 4 MB
    float* ca2  = pb + (size_t)NROWS * HD;               // 128 KB
    float* cb2  = ca2 + NROWS;                           // 128 KB
    __hip_bfloat16* Spart  = (__hip_bfloat16*)(cb2 + NROWS);     // 2 MB
    __hip_bfloat16* SpartT = Spart + (size_t)NC * D * D;         // 2 MB
    unsigned* cnt = (unsigned*)(SpartT + (size_t)NC * D * D);    // barrier ctrs
    float* out = (float*)d_out;

    // zero barrier counters each call (graph-capturable async memset)
    hipMemsetAsync(cnt, 0, 64, stream);
    fused_all<<<NBLK, 512, 0, stream>>>(z, Wmag, W1, b1, W2,
                                        pa, pb, ca2, cb2, Spart, SpartT,
                                        cnt, out);
}